// Round 4
// baseline (294.990 us; speedup 1.0000x reference)
//
#include <hip/hip_runtime.h>

// Volume renderer, octet-split version.
// R0-R2 all plateaued at ~105us with no pipe >25% busy; the structural
// constant was the wave-wide shuffle scan/reduction critical path. This
// version uses 8 threads per ray (lane octet); each thread serially
// composites 24 contiguous samples with the T-carry in-register (4-cyc FMA
// dependence). All octet outputs are linear in the entry transmittance, so
// each thread computes UNSCALED weights/partials, then a 4-shuffle exclusive
// product scan over the octet provides the scale, and a 15-shuffle butterfly
// reduces the 5 ray outputs. No LDS, no barriers, 524288 threads.

#define NRAYS 65536
#define L 192
#define BORDER_W 1e10f
#define EPS_F 1e-10f

__device__ __forceinline__ float fast_sigmoid(float x) {
    return __builtin_amdgcn_rcpf(1.0f + __expf(-x));
}

__global__ __launch_bounds__(256) void vol_render_kernel(
    const float* __restrict__ depth,   // [N, 192]
    const float* __restrict__ rgb,     // [N, 192, 3]
    const float* __restrict__ sigma,   // [N, 192]
    float* __restrict__ out)           // color N*3 | depth N | acc N | weights N*192
{
    const int t    = blockIdx.x * 256 + threadIdx.x;   // 524288 threads
    const int ray  = t >> 3;
    const int q    = t & 7;                            // octet slot: samples 24q..24q+23
    const int lane = threadIdx.x & 63;

    const float4* d4p = (const float4*)(depth + (size_t)ray * L + q * 24);
    const float4* s4p = (const float4*)(sigma + (size_t)ray * L + q * 24);
    const float4* r4p = (const float4*)(rgb + (size_t)ray * (L * 3) + q * 72);

    // upfront loads: 12 independent float4 loads -> deep MLP
    float4 d4[6], s4[6];
#pragma unroll
    for (int g = 0; g < 6; ++g) d4[g] = d4p[g];
#pragma unroll
    for (int g = 0; g < 6; ++g) s4[g] = s4p[g];

    // first depth of the NEXT octet = next lane's d4[0].x (q varies fastest)
    float nd = __shfl_down(d4[0].x, 1, 64);
    const bool last_octet = (q == 7);

    // ---- pass A: unscaled weights + unscaled depth/acc partials, T-carry in reg
    float4 w4[6];
    float T = 1.0f, dep_u = 0.0f, acc_u = 0.0f;
#pragma unroll
    for (int g = 0; g < 6; ++g) {
        float dnext = (g < 5) ? d4[g + 1].x : nd;
        float dl0 = d4[g].y - d4[g].x;
        float dl1 = d4[g].z - d4[g].y;
        float dl2 = d4[g].w - d4[g].z;
        float dl3 = (g == 5 && last_octet) ? BORDER_W : (dnext - d4[g].w);

        float e0 = __expf(-fmaxf(s4[g].x, 0.0f) * dl0);
        float e1 = __expf(-fmaxf(s4[g].y, 0.0f) * dl1);
        float e2 = __expf(-fmaxf(s4[g].z, 0.0f) * dl2);
        float e3 = __expf(-fmaxf(s4[g].w, 0.0f) * dl3);

        float w0 = (1.0f - e0) * T; T *= e0 + EPS_F;
        float w1 = (1.0f - e1) * T; T *= e1 + EPS_F;
        float w2 = (1.0f - e2) * T; T *= e2 + EPS_F;
        float w3 = (1.0f - e3) * T; T *= e3 + EPS_F;

        w4[g] = make_float4(w0, w1, w2, w3);
        dep_u += w0 * d4[g].x + w1 * d4[g].y + w2 * d4[g].z + w3 * d4[g].w;
        acc_u += w0 + w1 + w2 + w3;
    }

    // ---- exclusive product scan of octet survival totals (4 shuffles)
    float p = T;
#pragma unroll
    for (int off = 1; off < 8; off <<= 1) {
        float u = __shfl_up(p, off, 64);
        if ((lane & 7) >= off) p *= u;
    }
    float excl = __shfl_up(p, 1, 64);
    if ((lane & 7) == 0) excl = 1.0f;

    // ---- pass B: scale + store weights, accumulate color
    float* wp = out + (size_t)NRAYS * 5 + (size_t)ray * L + q * 24;
    float col0 = 0.f, col1 = 0.f, col2 = 0.f;
#pragma unroll
    for (int g = 0; g < 6; ++g) {
        float4 w = make_float4(excl * w4[g].x, excl * w4[g].y,
                               excl * w4[g].z, excl * w4[g].w);
        ((float4*)wp)[g] = w;

        float4 ra = r4p[3 * g + 0];   // s0c0 s0c1 s0c2 s1c0
        float4 rb = r4p[3 * g + 1];   // s1c1 s1c2 s2c0 s2c1
        float4 rc = r4p[3 * g + 2];   // s2c2 s3c0 s3c1 s3c2
        col0 += w.x * fast_sigmoid(ra.x) + w.y * fast_sigmoid(ra.w)
              + w.z * fast_sigmoid(rb.z) + w.w * fast_sigmoid(rc.y);
        col1 += w.x * fast_sigmoid(ra.y) + w.y * fast_sigmoid(rb.x)
              + w.z * fast_sigmoid(rb.w) + w.w * fast_sigmoid(rc.z);
        col2 += w.x * fast_sigmoid(ra.z) + w.y * fast_sigmoid(rb.y)
              + w.z * fast_sigmoid(rc.x) + w.w * fast_sigmoid(rc.w);
    }
    float dep = excl * dep_u;
    float acc = excl * acc_u;

    // ---- butterfly reduction within the octet (stays inside aligned octets)
#pragma unroll
    for (int off = 1; off < 8; off <<= 1) {
        col0 += __shfl_xor(col0, off, 64);
        col1 += __shfl_xor(col1, off, 64);
        col2 += __shfl_xor(col2, off, 64);
        dep  += __shfl_xor(dep,  off, 64);
        acc  += __shfl_xor(acc,  off, 64);
    }
    if (q == 0) {
        out[(size_t)ray * 3 + 0] = col0;
        out[(size_t)ray * 3 + 1] = col1;
        out[(size_t)ray * 3 + 2] = col2;
        out[(size_t)NRAYS * 3 + ray] = dep;
        out[(size_t)NRAYS * 4 + ray] = acc;
    }
}

extern "C" void kernel_launch(void* const* d_in, const int* in_sizes, int n_in,
                              void* d_out, int out_size, void* d_ws, size_t ws_size,
                              hipStream_t stream) {
    const float* depth = (const float*)d_in[0];
    const float* rgb   = (const float*)d_in[1];
    const float* sigma = (const float*)d_in[2];
    float* out = (float*)d_out;

    dim3 grid((NRAYS * 8) / 256);   // 2048 blocks, 8 threads per ray
    dim3 block(256);
    vol_render_kernel<<<grid, block, 0, stream>>>(depth, rgb, sigma, out);
}